// Round 13
// baseline (193.016 us; speedup 1.0000x reference)
//
#include <hip/hip_runtime.h>
#include <hip/hip_bf16.h>

#define NB 4096
#define NT 50
#define NH 128
#define NINT 4
#define ROWS 64  // batch rows per block

typedef float f32x4 __attribute__((ext_vector_type(4)));
typedef __bf16 bf16x8 __attribute__((ext_vector_type(8)));
typedef short short8 __attribute__((ext_vector_type(8)));
typedef short short4s __attribute__((ext_vector_type(4)));

#define L2E 1.4426950408889634f

__device__ __forceinline__ float frcp(float x) { return __builtin_amdgcn_rcpf(x); }

// exp2(-x): v_exp_f32 computes 2^x; neg is a free src modifier.
__device__ __forceinline__ float exp2neg(float x) {
  float r;
  asm("v_exp_f32 %0, -%1" : "=v"(r) : "v"(x));
  return r;
}

__device__ __forceinline__ unsigned short bfbits(float f) {
  __bf16 b = (__bf16)f;  // native RTNE; pairs pack to v_cvt_pk_bf16_f32
  return __builtin_bit_cast(unsigned short, b);
}

// Grid: 256 blocks = NINT(4) * (NB/64).  Block: 512 threads = 8 waves, 1/CU.
// R13 = R12 + MFMA-GATE: the interest-gate logits [4 x 64rows] = w_int @ x are
// computed by 4 extra MFMAs per m using a zero-padded w_int A-frag and the
// SAME x B-frags the gi MFMAs already load -> deletes gate_from (16
// ds_read_b128 + 64 FMA + 12 shuffles per thread-step), wintl, gbuf.  Lanes
// l4==0 hold all 4 interest logits for row l15 (D: oc=(l>>4)*4+j, row=l&15);
// local softmax (exp2, 10*log2e folded into wg) + one shfl broadcast.
// R9 LESSON: inline-asm v_mfma bypasses the MFMA hazard recognizer -> NaN.
// R3-R5 LESSON: weight-resident design needs the (512,2) 256-reg budget.
__global__ __launch_bounds__(512, 2)
void gru_fused(const int* __restrict__ inputs, const float* __restrict__ emb,
               const float* __restrict__ w_int, const float* __restrict__ w_ih,
               const float* __restrict__ w_hh, const float* __restrict__ b_ih,
               const float* __restrict__ b_hh, const float* __restrict__ h0,
               float* __restrict__ out) {
  __shared__ unsigned short xs[2][ROWS * NH];  // 32 KB x tile, bf16, swizzled
  __shared__ unsigned short hs[2][ROWS * NH];  // 32 KB h tile, bf16, swizzled
  __shared__ int idxs[NT * ROWS];              // 12.8 KB token ids

  const int tid = threadIdx.x;
  const int bx = blockIdx.x;
  const int I = bx >> 6;          // interest 0..3
  const int R0 = (bx & 63) * ROWS;
  const int w = tid >> 6;         // wave 0..7
  const int lane = tid & 63;
  const int l15 = lane & 15;
  const int l4 = lane >> 4;
  const int oc0 = w * 16 + l4 * 4;  // lane's first h-col (owns oc0..oc0+3)

  // staging/gather mapping: 8 threads per row, 16 floats (64B) each
  const int sr = tid >> 3;  // row 0..63
  const int sp = tid & 7;   // segment

  // ---- token indices ----
  for (int e = tid; e < NT * ROWS; e += 512) {
    int t = e >> 6, r = e & (ROWS - 1);
    idxs[e] = inputs[(size_t)(R0 + r) * NT + t];
  }
  __syncthreads();

  // ---- persistent weight fragments (96 VGPR, MFMA A-operands) + bias
  //      vectors, PRE-SCALED: gates r,i: *log2e; gate n: *2*log2e.
  //      A-frag: lane holds row(=oc_local)=lane&15, k=(lane>>4)*8 + 0..7
  bf16x8 wih[3][4], whh[3][4];
  f32x4 bR, bI, bNI, bNH;  // per-j bias vectors (j indexes oc0+j)
  {
    const float gs[3] = {L2E, L2E, 2.0f * L2E};
    #pragma unroll
    for (int g = 0; g < 3; ++g) {
      int oc = g * NH + w * 16 + l15;
      #pragma unroll
      for (int kk = 0; kk < 4; ++kk) {
        int k0 = kk * 32 + l4 * 8;
        const float* pi = w_ih + ((size_t)(I * 384 + oc) * NH + k0);
        const float* ph = w_hh + ((size_t)(I * 384 + oc) * NH + k0);
        bf16x8 si, sh;
        #pragma unroll
        for (int e = 0; e < 8; ++e) {
          si[e] = (__bf16)(pi[e] * gs[g]);
          sh[e] = (__bf16)(ph[e] * gs[g]);
        }
        wih[g][kk] = si;
        whh[g][kk] = sh;
      }
    }
    #pragma unroll
    for (int j = 0; j < 4; ++j) {
      bR[j] = (b_ih[I * 384 + oc0 + j] + b_hh[I * 384 + oc0 + j]) * L2E;
      bI[j] = (b_ih[I * 384 + NH + oc0 + j] + b_hh[I * 384 + NH + oc0 + j]) * L2E;
      bNI[j] = b_ih[I * 384 + 2 * NH + oc0 + j] * (2.0f * L2E);
      bNH[j] = b_hh[I * 384 + 2 * NH + oc0 + j] * (2.0f * L2E);
    }
  }

  // ---- w_interest A-frag (16 regs): interest i in row i (i<4), rows 4-15
  //      ZERO; scaled by 10*log2e so softmax is pure exp2 ----
  bf16x8 wg[4];
  #pragma unroll
  for (int kk = 0; kk < 4; ++kk) {
    bf16x8 f;
    #pragma unroll
    for (int e = 0; e < 8; ++e) {
      float v = (l15 < NINT)
                    ? w_int[l15 * NH + kk * 32 + l4 * 8 + e] * (10.0f * L2E)
                    : 0.0f;
      f[e] = (__bf16)v;
    }
    wg[kk] = f;
  }

  // ---- h0 master (fp32 regs) + initial bf16 LDS copy ----
  // Transposed D layout: row(batch) = m*16 + (lane&15), hcol = oc0 + j
  float hm[4][4];
  #pragma unroll
  for (int m = 0; m < 4; ++m) {
    int row = m * 16 + l15;
    short4s p;
    #pragma unroll
    for (int j = 0; j < 4; ++j) {
      float v = h0[((size_t)I * NB + R0 + row) * NH + oc0 + j];
      hm[m][j] = v;
      p[j] = (short)bfbits(v);
    }
    *(short4s*)&hs[0][(row * NH + oc0) ^ ((row & 7) << 3)] = p;
  }

  // ---- stage x(0) ----
  {
    const float4* src = (const float4*)(emb + (size_t)idxs[sr] * NH + sp * 16);
    float4 v0 = src[0], v1 = src[1], v2 = src[2], v3 = src[3];
    short8 s0, s1;
    s0[0] = bfbits(v0.x); s0[1] = bfbits(v0.y); s0[2] = bfbits(v0.z); s0[3] = bfbits(v0.w);
    s0[4] = bfbits(v1.x); s0[5] = bfbits(v1.y); s0[6] = bfbits(v1.z); s0[7] = bfbits(v1.w);
    s1[0] = bfbits(v2.x); s1[1] = bfbits(v2.y); s1[2] = bfbits(v2.z); s1[3] = bfbits(v2.w);
    s1[4] = bfbits(v3.x); s1[5] = bfbits(v3.y); s1[6] = bfbits(v3.z); s1[7] = bfbits(v3.w);
    int base = sr * NH + sp * 16;
    int sw = (sr & 7) << 3;
    *(short8*)&xs[0][base ^ sw] = s0;
    *(short8*)&xs[0][(base + 8) ^ sw] = s1;
  }
  __syncthreads();

  // ---- main recurrence ----
  for (int t = 0; t < NT; ++t) {
    const int cur = t & 1, nxt = cur ^ 1;
    const bool pf = (t + 1 < NT);

    // prefetch x(t+1) into regs; latency hides under the MFMAs
    float4 v0, v1, v2, v3;
    if (pf) {
      const float4* src =
          (const float4*)(emb + (size_t)idxs[(t + 1) * ROWS + sr] * NH + sp * 16);
      v0 = src[0]; v1 = src[1]; v2 = src[2]; v3 = src[3];
    }

    const unsigned short* hsc = hs[cur];
    const unsigned short* xsc = xs[cur];
    unsigned short* hsn = hs[nxt];

    #pragma unroll
    for (int m = 0; m < 4; ++m) {
      f32x4 aR = bR, aI = bI, aNI = bNI, aNH = bNH;  // vector bias init
      f32x4 aG = f32x4{0.0f, 0.0f, 0.0f, 0.0f};     // gate logits

      int brow = m * 16 + l15;        // B-frag col = batch row
      int blin = brow * NH + l4 * 8;  // bits 3-4
      int sw2 = (brow & 7) << 3;      // bits 3-5
      __builtin_amdgcn_s_setprio(1);
      #pragma unroll
      for (int kk = 0; kk < 4; ++kk) {
        int e = (blin + kk * 32) ^ sw2;  // kk*32: bits 5-6, carry-free; XOR full index
        bf16x8 bh = __builtin_bit_cast(bf16x8, *(const short8*)&hsc[e]);
        bf16x8 bx = __builtin_bit_cast(bf16x8, *(const short8*)&xsc[e]);
        // TRANSPOSED: A = weights, B = data -> D[oc][row]
        aG = __builtin_amdgcn_mfma_f32_16x16x32_bf16(wg[kk], bx, aG, 0, 0, 0);
        aR = __builtin_amdgcn_mfma_f32_16x16x32_bf16(wih[0][kk], bx, aR, 0, 0, 0);
        aR = __builtin_amdgcn_mfma_f32_16x16x32_bf16(whh[0][kk], bh, aR, 0, 0, 0);
        aI = __builtin_amdgcn_mfma_f32_16x16x32_bf16(wih[1][kk], bx, aI, 0, 0, 0);
        aI = __builtin_amdgcn_mfma_f32_16x16x32_bf16(whh[1][kk], bh, aI, 0, 0, 0);
        aNI = __builtin_amdgcn_mfma_f32_16x16x32_bf16(wih[2][kk], bx, aNI, 0, 0, 0);
        aNH = __builtin_amdgcn_mfma_f32_16x16x32_bf16(whh[2][kk], bh, aNH, 0, 0, 0);
      }
      __builtin_amdgcn_s_setprio(0);

      // gate softmax from aG (valid on lanes l4==0; logits pre-scaled by
      // 10*log2e).  Computed on all lanes, broadcast from lane l15.
      float s0 = aG[0], s1 = aG[1], s2 = aG[2], s3 = aG[3];
      float mx = fmaxf(fmaxf(s0, s1), fmaxf(s2, s3));
      float e0 = exp2neg(mx - s0), e1 = exp2neg(mx - s1);
      float e2 = exp2neg(mx - s2), e3 = exp2neg(mx - s3);
      float sel = (I == 0) ? e0 : (I == 1) ? e1 : (I == 2) ? e2 : e3;
      float gvl = sel * frcp(e0 + e1 + e2 + e3);
      gvl = (gvl > 0.01f) ? gvl : 0.0f;
      const float gv = __shfl(gvl, l15, 64);  // broadcast row gate to all l4

      short4s p;
      #pragma unroll
      for (int j = 0; j < 4; ++j) {
        float rg = frcp(1.0f + exp2neg(aR[j]));
        float ig = frcp(1.0f + exp2neg(aI[j]));
        float an = fmaf(rg, aNH[j], aNI[j]);
        float ng = fmaf(2.0f, frcp(1.0f + exp2neg(an)), -1.0f);
        float c = gv * ig;  // gv pre-thresholded
        float hy = fmaf(c, ng - hm[m][j], hm[m][j]);
        hm[m][j] = hy;
        p[j] = (short)bfbits(hy);
      }
      // packed h-writeback: 4 consecutive h-cols, one ds_write_b64
      *(short4s*)&hsn[(brow * NH + oc0) ^ sw2] = p;
    }

    if (pf) {
      short8 s0, s1;
      s0[0] = bfbits(v0.x); s0[1] = bfbits(v0.y); s0[2] = bfbits(v0.z); s0[3] = bfbits(v0.w);
      s0[4] = bfbits(v1.x); s0[5] = bfbits(v1.y); s0[6] = bfbits(v1.z); s0[7] = bfbits(v1.w);
      s1[0] = bfbits(v2.x); s1[1] = bfbits(v2.y); s1[2] = bfbits(v2.z); s1[3] = bfbits(v2.w);
      s1[4] = bfbits(v3.x); s1[5] = bfbits(v3.y); s1[6] = bfbits(v3.z); s1[7] = bfbits(v3.w);
      int base = sr * NH + sp * 16;
      int sw = (sr & 7) << 3;
      *(short8*)&xs[nxt][base ^ sw] = s0;
      *(short8*)&xs[nxt][(base + 8) ^ sw] = s1;
    }
    __syncthreads();
  }

  // ---- epilogue: out[b][I][h], float4 per m ----
  #pragma unroll
  for (int m = 0; m < 4; ++m) {
    int row = m * 16 + l15;
    f32x4 o;
    #pragma unroll
    for (int j = 0; j < 4; ++j) o[j] = hm[m][j];
    *(f32x4*)&out[(size_t)(R0 + row) * (NINT * NH) + I * NH + oc0] = o;
  }
}

extern "C" void kernel_launch(void* const* d_in, const int* in_sizes, int n_in,
                              void* d_out, int out_size, void* d_ws, size_t ws_size,
                              hipStream_t stream) {
  const int* inputs = (const int*)d_in[0];
  const float* emb = (const float*)d_in[1];
  const float* w_int = (const float*)d_in[2];
  const float* w_ih = (const float*)d_in[3];
  const float* w_hh = (const float*)d_in[4];
  const float* b_ih = (const float*)d_in[5];
  const float* b_hh = (const float*)d_in[6];
  const float* h0 = (const float*)d_in[7];
  float* out = (float*)d_out;

  dim3 grid(NINT * (NB / ROWS));  // 256 blocks, one per CU
  dim3 block(512);
  gru_fused<<<grid, block, 0, stream>>>(inputs, emb, w_int, w_ih, w_hh, b_ih,
                                        b_hh, h0, out);
}